// Round 9
// baseline (337.433 us; speedup 1.0000x reference)
//
#include <hip/hip_runtime.h>
#include <hip/hip_bf16.h>
#include <cstddef>
#include <cstdint>

// B=2, S=2048, D=1024, H=16, DK=64, FF=4096. Rows = 4096.
// All GEMMs + attention use the 2-buffer raw-barrier vmcnt(N) pipeline.
// Attention: 64 q/block (16 q/wave) -> 1024 blocks, 40KB LDS, 4 blocks/CU.
//
// Workspace (72 MB):
//   [0,2)   WqT bf16 [1024][1024]  \
//   [2,4)   WkT                     > contiguous => WqkvT [3072][1024]
//   [4,6)   WvT                    /
//   [6,8)   WoT
//   [8,16)  W1T bf16 [4096][1024]
//   [16,24) W2T bf16 [1024][4096]
//   [24,32) nX  bf16 [4096][1024]   (dead after FFN1 -> reused as P0)
//   [32,56) QKV bf16 [4096][3072]
//   [56,64) Cx  bf16 [4096][1024]
//   [64,72) Vt  bf16 [2][16][64][2048]  (dead after attn -> reused as P1)
//   [32,64) Hb  bf16 [4096][4096]
#define ROWS 4096
#define DMODEL 1024
#define SEQ 2048
#define NHEAD 16
#define FFDIM 4096
#define QKVS 3072

typedef __bf16 bf16x8 __attribute__((ext_vector_type(8)));
typedef __bf16 bf16x4v __attribute__((ext_vector_type(4)));
typedef float f32x4 __attribute__((ext_vector_type(4)));

#if __has_builtin(__builtin_amdgcn_exp2f)
#define EXP2(x) __builtin_amdgcn_exp2f(x)
#else
#define EXP2(x) exp2f(x)
#endif

__device__ __forceinline__ float bf2f(unsigned short u) {
    unsigned int v = ((unsigned int)u) << 16;
    return __builtin_bit_cast(float, v);
}
__device__ __forceinline__ unsigned short f2bf(float f) {
    unsigned int v = __builtin_bit_cast(unsigned int, f);
    v = v + 0x7fffu + ((v >> 16) & 1u);  // RNE
    return (unsigned short)(v >> 16);
}

// async global->LDS, 16B/lane; LDS dest = wave-uniform base + lane*16
__device__ __forceinline__ void gl_lds16(const unsigned short* g, unsigned short* l) {
    auto gp = reinterpret_cast<const unsigned int __attribute__((address_space(1)))*>(
        reinterpret_cast<uintptr_t>(g));
    auto lp = reinterpret_cast<unsigned int __attribute__((address_space(3)))*>(
        reinterpret_cast<uintptr_t>(l));
    __builtin_amdgcn_global_load_lds(gp, lp, 16, 0, 0);
}

// ---------------- weight transposes + LN1, one launch ----------------
__global__ __launch_bounds__(256) void pre_kernel(
    const float* __restrict__ Wq, const float* __restrict__ Wk,
    const float* __restrict__ Wv, const float* __restrict__ Wo,
    const float* __restrict__ W1, const float* __restrict__ W2,
    unsigned short* WqT, unsigned short* WkT, unsigned short* WvT,
    unsigned short* WoT, unsigned short* W1T, unsigned short* W2T,
    const float* __restrict__ X, const float* __restrict__ g1,
    const float* __restrict__ be1, unsigned short* __restrict__ nX) {
    int bid = blockIdx.x;
    int tid = threadIdx.x;
    if (bid >= 12288) {
        int row = bid - 12288;
        const float4* x4 = (const float4*)(X + (size_t)row * DMODEL);
        float4 v = x4[tid];
        float s = v.x + v.y + v.z + v.w;
        float s2 = v.x * v.x + v.y * v.y + v.z * v.z + v.w * v.w;
#pragma unroll
        for (int off = 32; off > 0; off >>= 1) {
            s += __shfl_down(s, off, 64);
            s2 += __shfl_down(s2, off, 64);
        }
        __shared__ float sh[8];
        int wave = tid >> 6, lane = tid & 63;
        if (lane == 0) { sh[wave] = s; sh[4 + wave] = s2; }
        __syncthreads();
        float ts = sh[0] + sh[1] + sh[2] + sh[3];
        float ts2 = sh[4] + sh[5] + sh[6] + sh[7];
        float mean = ts * (1.0f / DMODEL);
        float var = ts2 * (1.0f / DMODEL) - mean * mean;
        float rstd = rsqrtf(var + 1e-5f);
        float4 gv = ((const float4*)g1)[tid];
        float4 bv = ((const float4*)be1)[tid];
        ushort4 o;
        o.x = f2bf((v.x - mean) * rstd * gv.x + bv.x);
        o.y = f2bf((v.y - mean) * rstd * gv.y + bv.y);
        o.z = f2bf((v.z - mean) * rstd * gv.z + bv.z);
        o.w = f2bf((v.w - mean) * rstd * gv.w + bv.w);
        ((ushort4*)(nX + (size_t)row * DMODEL))[tid] = o;
        return;
    }
    const float* W;
    unsigned short* WT;
    int K, N, t, nsh;
    if (bid < 4096) {
        int w = bid >> 10;
        t = bid & 1023;
        W = w == 0 ? Wq : w == 1 ? Wk : w == 2 ? Wv : Wo;
        WT = w == 0 ? WqT : w == 1 ? WkT : w == 2 ? WvT : WoT;
        K = 1024; N = 1024; nsh = 5;
    } else if (bid < 8192) {
        t = bid - 4096; W = W1; WT = W1T; K = 1024; N = 4096; nsh = 7;
    } else {
        t = bid - 8192; W = W2; WT = W2T; K = 4096; N = 1024; nsh = 5;
    }
    int nx = t & ((1 << nsh) - 1), ky = t >> nsh;
    int n0 = nx * 32, k0 = ky * 32;
    __shared__ float tl[32][33];
    int tx = tid & 31, ty = tid >> 5;
#pragma unroll
    for (int i = 0; i < 32; i += 8) tl[ty + i][tx] = W[(size_t)(k0 + ty + i) * N + n0 + tx];
    __syncthreads();
#pragma unroll
    for (int i = 0; i < 32; i += 8)
        WT[(size_t)(n0 + ty + i) * K + k0 + tx] = f2bf(tl[tx][ty + i]);
}

// ---------------- LayerNorm (LN2): fp32 in -> bf16 out ----------------
__global__ __launch_bounds__(256) void ln_kernel(const float* __restrict__ X,
                                                 const float* __restrict__ g,
                                                 const float* __restrict__ beta,
                                                 unsigned short* __restrict__ out) {
    int row = blockIdx.x, tid = threadIdx.x;
    const float4* x4 = (const float4*)(X + (size_t)row * DMODEL);
    float4 v = x4[tid];
    float s = v.x + v.y + v.z + v.w;
    float s2 = v.x * v.x + v.y * v.y + v.z * v.z + v.w * v.w;
#pragma unroll
    for (int off = 32; off > 0; off >>= 1) {
        s += __shfl_down(s, off, 64);
        s2 += __shfl_down(s2, off, 64);
    }
    __shared__ float sh[8];
    int wave = tid >> 6, lane = tid & 63;
    if (lane == 0) { sh[wave] = s; sh[4 + wave] = s2; }
    __syncthreads();
    float ts = sh[0] + sh[1] + sh[2] + sh[3];
    float ts2 = sh[4] + sh[5] + sh[6] + sh[7];
    float mean = ts * (1.0f / DMODEL);
    float var = ts2 * (1.0f / DMODEL) - mean * mean;
    float rstd = rsqrtf(var + 1e-5f);
    float4 gv = ((const float4*)g)[tid];
    float4 bv = ((const float4*)beta)[tid];
    ushort4 o;
    o.x = f2bf((v.x - mean) * rstd * gv.x + bv.x);
    o.y = f2bf((v.y - mean) * rstd * gv.y + bv.y);
    o.z = f2bf((v.z - mean) * rstd * gv.z + bv.z);
    o.w = f2bf((v.w - mean) * rstd * gv.w + bv.w);
    ((ushort4*)(out + (size_t)row * DMODEL))[tid] = o;
}

// ------- bf16 MFMA GEMM, 2-buf vmcnt(4) pipeline: C = epi(A @ BT^T) -------
enum { EP_BF16 = 0, EP_RESID_F32 = 1, EP_RELUBIAS_BF16 = 2, EP_BIASRESID_F32 = 3 };

template <int EP>
__global__ __launch_bounds__(256) void mm_kernel(const unsigned short* __restrict__ A,
                                                 const unsigned short* __restrict__ BT,
                                                 const float* __restrict__ bias,
                                                 const float* __restrict__ resid,
                                                 unsigned short* __restrict__ Cb,
                                                 float* __restrict__ Cf,
                                                 int M, int N, int K) {
    __shared__ unsigned short smem[2 * 8192];  // buf: As 4096 | Bs 4096
    int tid = threadIdx.x;
    int wave = tid >> 6, lane = tid & 63;
    int quad = lane >> 4, m16 = lane & 15;
    int wm = wave >> 1, wn = wave & 1;
    int row0 = blockIdx.y * 128, col0 = blockIdx.x * 128;

    int f0 = wave * 64 + lane;
    int rA = f0 >> 2, kc = f0 & 3;
    const unsigned short* Ab = A + (size_t)(row0 + rA) * K + kc * 8;
    const unsigned short* Bb = BT + (size_t)(col0 + rA) * K + kc * 8;

    f32x4 acc[4][4];
#pragma unroll
    for (int i = 0; i < 4; i++)
#pragma unroll
        for (int j = 0; j < 4; j++) acc[i][j] = (f32x4){0.f, 0.f, 0.f, 0.f};

    auto stage = [&](int k0, int buf) {
        unsigned short* AsW = smem + buf * 8192 + wave * 512;
        unsigned short* BsW = smem + buf * 8192 + 4096 + wave * 512;
        gl_lds16(Ab + k0, AsW);
        gl_lds16(Ab + (size_t)64 * K + k0, AsW + 2048);
        gl_lds16(Bb + k0, BsW);
        gl_lds16(Bb + (size_t)64 * K + k0, BsW + 2048);
    };

    stage(0, 0);
    int buf = 0;
    for (int k0 = 0; k0 < K; k0 += 32) {
        if (k0 + 32 < K) {
            stage(k0 + 32, buf ^ 1);  // prefetch stays in flight across barrier
            __asm__ volatile("s_waitcnt vmcnt(4)" ::: "memory");
        } else {
            __asm__ volatile("s_waitcnt vmcnt(0)" ::: "memory");
        }
        __builtin_amdgcn_s_barrier();
        unsigned short* As = smem + buf * 8192;
        unsigned short* Bs = As + 4096;
        bf16x8 af[4], bfr[4];
#pragma unroll
        for (int i = 0; i < 4; i++)
            af[i] = *(const bf16x8*)&As[(wm * 64 + i * 16 + m16) * 32 + quad * 8];
#pragma unroll
        for (int j = 0; j < 4; j++)
            bfr[j] = *(const bf16x8*)&Bs[(wn * 64 + j * 16 + m16) * 32 + quad * 8];
#pragma unroll
        for (int i = 0; i < 4; i++)
#pragma unroll
            for (int j = 0; j < 4; j++)
                acc[i][j] = __builtin_amdgcn_mfma_f32_16x16x32_bf16(af[i], bfr[j], acc[i][j], 0, 0, 0);
        __builtin_amdgcn_s_barrier();  // reads done before buf is restaged
        buf ^= 1;
    }

#pragma unroll
    for (int i = 0; i < 4; i++) {
        int rbase = row0 + wm * 64 + i * 16 + quad * 4;
#pragma unroll
        for (int j = 0; j < 4; j++) {
            int col = col0 + wn * 64 + j * 16 + m16;
            float bv = (EP == EP_RELUBIAS_BF16 || EP == EP_BIASRESID_F32) ? bias[col] : 0.f;
#pragma unroll
            for (int r = 0; r < 4; r++) {
                size_t idx = (size_t)(rbase + r) * N + col;
                float v = acc[i][j][r];
                if (EP == EP_BF16) {
                    Cb[idx] = f2bf(v);
                } else if (EP == EP_RESID_F32) {
                    Cf[idx] = v + resid[idx];
                } else if (EP == EP_RELUBIAS_BF16) {
                    Cb[idx] = f2bf(fmaxf(v + bv, 0.f));
                } else {
                    Cf[idx] = v + bv + resid[idx];
                }
            }
        }
    }
}

// ------- split-K (z=2) 128x128 GEMM, pipelined -> bf16 partials -------
__global__ __launch_bounds__(256) void mmsk_kernel(const unsigned short* __restrict__ A,
                                                   const unsigned short* __restrict__ BT,
                                                   unsigned short* __restrict__ P0,
                                                   unsigned short* __restrict__ P1,
                                                   int M, int N, int K) {
    __shared__ unsigned short smem[2 * 8192];
    int tid = threadIdx.x;
    int wave = tid >> 6, lane = tid & 63;
    int quad = lane >> 4, m16 = lane & 15;
    int wm = wave >> 1, wn = wave & 1;
    int row0 = blockIdx.y * 128, col0 = blockIdx.x * 128;
    int kh = K >> 1;
    int kst = blockIdx.z * kh;

    int f0 = wave * 64 + lane;
    int rA = f0 >> 2, kc = f0 & 3;
    const unsigned short* Ab = A + (size_t)(row0 + rA) * K + kst + kc * 8;
    const unsigned short* Bb = BT + (size_t)(col0 + rA) * K + kst + kc * 8;

    f32x4 acc[4][4];
#pragma unroll
    for (int i = 0; i < 4; i++)
#pragma unroll
        for (int j = 0; j < 4; j++) acc[i][j] = (f32x4){0.f, 0.f, 0.f, 0.f};

    auto stage = [&](int k0, int buf) {
        unsigned short* AsW = smem + buf * 8192 + wave * 512;
        unsigned short* BsW = smem + buf * 8192 + 4096 + wave * 512;
        gl_lds16(Ab + k0, AsW);
        gl_lds16(Ab + (size_t)64 * K + k0, AsW + 2048);
        gl_lds16(Bb + k0, BsW);
        gl_lds16(Bb + (size_t)64 * K + k0, BsW + 2048);
    };

    stage(0, 0);
    int buf = 0;
    for (int k0 = 0; k0 < kh; k0 += 32) {
        if (k0 + 32 < kh) {
            stage(k0 + 32, buf ^ 1);
            __asm__ volatile("s_waitcnt vmcnt(4)" ::: "memory");
        } else {
            __asm__ volatile("s_waitcnt vmcnt(0)" ::: "memory");
        }
        __builtin_amdgcn_s_barrier();
        unsigned short* As = smem + buf * 8192;
        unsigned short* Bs = As + 4096;
        bf16x8 af[4], bfr[4];
#pragma unroll
        for (int i = 0; i < 4; i++)
            af[i] = *(const bf16x8*)&As[(wm * 64 + i * 16 + m16) * 32 + quad * 8];
#pragma unroll
        for (int j = 0; j < 4; j++)
            bfr[j] = *(const bf16x8*)&Bs[(wn * 64 + j * 16 + m16) * 32 + quad * 8];
#pragma unroll
        for (int i = 0; i < 4; i++)
#pragma unroll
            for (int j = 0; j < 4; j++)
                acc[i][j] = __builtin_amdgcn_mfma_f32_16x16x32_bf16(af[i], bfr[j], acc[i][j], 0, 0, 0);
        __builtin_amdgcn_s_barrier();
        buf ^= 1;
    }

    unsigned short* P = blockIdx.z ? P1 : P0;
#pragma unroll
    for (int i = 0; i < 4; i++) {
        int rbase = row0 + wm * 64 + i * 16 + quad * 4;
#pragma unroll
        for (int j = 0; j < 4; j++) {
            int col = col0 + wn * 64 + j * 16 + m16;
#pragma unroll
            for (int r = 0; r < 4; r++)
                P[(size_t)(rbase + r) * N + col] = f2bf(acc[i][j][r]);
        }
    }
}

// ---------------- reduce: out += P0 + P1 + b2 ----------------
__global__ __launch_bounds__(256) void red2_kernel(const unsigned short* __restrict__ P0,
                                                   const unsigned short* __restrict__ P1,
                                                   const float* __restrict__ b2,
                                                   float* __restrict__ out) {
    size_t i4 = (size_t)blockIdx.x * 256 + threadIdx.x;
    ushort4 a = ((const ushort4*)P0)[i4];
    ushort4 c = ((const ushort4*)P1)[i4];
    float4 o = ((float4*)out)[i4];
    float4 bb = ((const float4*)b2)[i4 & 255];
    o.x += bf2f(a.x) + bf2f(c.x) + bb.x;
    o.y += bf2f(a.y) + bf2f(c.y) + bb.y;
    o.z += bf2f(a.z) + bf2f(c.z) + bb.z;
    o.w += bf2f(a.w) + bf2f(c.w) + bb.w;
    ((float4*)out)[i4] = o;
}

// ------- 128x64-tile GEMM for Wo (N=1024, K=1024), pipelined -------
template <int EP>
__global__ __launch_bounds__(256) void mm64_kernel(const unsigned short* __restrict__ A,
                                                   const unsigned short* __restrict__ BT,
                                                   const float* __restrict__ bias,
                                                   const float* __restrict__ resid,
                                                   unsigned short* __restrict__ Cb,
                                                   float* __restrict__ Cf,
                                                   int M, int N, int K) {
    __shared__ unsigned short smem[2 * 6144];  // buf: As 4096 | Bs 2048
    int tid = threadIdx.x;
    int wave = tid >> 6, lane = tid & 63;
    int quad = lane >> 4, m16 = lane & 15;
    int row0 = blockIdx.y * 128, col0 = blockIdx.x * 64;

    int f0 = wave * 64 + lane;
    int rA = f0 >> 2, kc = f0 & 3;
    const unsigned short* Ab = A + (size_t)(row0 + rA) * K + kc * 8;
    const unsigned short* Bb = BT + (size_t)(col0 + rA) * K + kc * 8;

    f32x4 acc[2][4];
#pragma unroll
    for (int i = 0; i < 2; i++)
#pragma unroll
        for (int j = 0; j < 4; j++) acc[i][j] = (f32x4){0.f, 0.f, 0.f, 0.f};

    auto stage = [&](int k0, int buf) {
        unsigned short* AsW = smem + buf * 6144 + wave * 512;
        unsigned short* BsW = smem + buf * 6144 + 4096 + wave * 512;
        gl_lds16(Ab + k0, AsW);
        gl_lds16(Ab + (size_t)64 * K + k0, AsW + 2048);
        gl_lds16(Bb + k0, BsW);
    };

    stage(0, 0);
    int buf = 0;
    for (int k0 = 0; k0 < K; k0 += 32) {
        if (k0 + 32 < K) {
            stage(k0 + 32, buf ^ 1);
            __asm__ volatile("s_waitcnt vmcnt(3)" ::: "memory");
        } else {
            __asm__ volatile("s_waitcnt vmcnt(0)" ::: "memory");
        }
        __builtin_amdgcn_s_barrier();
        unsigned short* As = smem + buf * 6144;
        unsigned short* Bs = As + 4096;
        bf16x8 af[2], bfr[4];
#pragma unroll
        for (int i = 0; i < 2; i++)
            af[i] = *(const bf16x8*)&As[(wave * 32 + i * 16 + m16) * 32 + quad * 8];
#pragma unroll
        for (int j = 0; j < 4; j++)
            bfr[j] = *(const bf16x8*)&Bs[(j * 16 + m16) * 32 + quad * 8];
#pragma unroll
        for (int i = 0; i < 2; i++)
#pragma unroll
            for (int j = 0; j < 4; j++)
                acc[i][j] = __builtin_amdgcn_mfma_f32_16x16x32_bf16(af[i], bfr[j], acc[i][j], 0, 0, 0);
        __builtin_amdgcn_s_barrier();
        buf ^= 1;
    }

#pragma unroll
    for (int i = 0; i < 2; i++) {
        int rbase = row0 + wave * 32 + i * 16 + quad * 4;
#pragma unroll
        for (int j = 0; j < 4; j++) {
            int col = col0 + j * 16 + m16;
            float bv = (EP == EP_RELUBIAS_BF16 || EP == EP_BIASRESID_F32) ? bias[col] : 0.f;
#pragma unroll
            for (int r = 0; r < 4; r++) {
                size_t idx = (size_t)(rbase + r) * N + col;
                float v = acc[i][j][r];
                if (EP == EP_BF16) {
                    Cb[idx] = f2bf(v);
                } else if (EP == EP_RESID_F32) {
                    Cf[idx] = v + resid[idx];
                } else if (EP == EP_RELUBIAS_BF16) {
                    Cb[idx] = f2bf(fmaxf(v + bv, 0.f));
                } else {
                    Cf[idx] = v + bv + resid[idx];
                }
            }
        }
    }
}

// ---------------- V transpose: QKV[.,2048+h*64+d] -> Vt[b][h][d][s] ----------------
__global__ __launch_bounds__(256) void vtrans_kernel(const unsigned short* __restrict__ QKV,
                                                     unsigned short* __restrict__ Vt) {
    __shared__ unsigned short t[64][68];
    int tid = threadIdx.x;
    int s0 = blockIdx.x * 64, bh = blockIdx.y;
    int b = bh >> 4, h = bh & 15;
    const unsigned short* src = QKV + (size_t)(b * SEQ + s0) * QKVS + 2048 + h * 64;
#pragma unroll
    for (int c = 0; c < 4; c++) {
        int idx = c * 256 + tid;
        int sr = idx >> 4, c4 = idx & 15;
        *(ushort4*)&t[sr][c4 * 4] = *(const ushort4*)(src + (size_t)sr * QKVS + c4 * 4);
    }
    __syncthreads();
#pragma unroll
    for (int c = 0; c < 4; c++) {
        int idx = c * 256 + tid;
        int d = idx >> 4, sq = idx & 15;
        ushort4 o;
        o.x = t[sq * 4 + 0][d];
        o.y = t[sq * 4 + 1][d];
        o.z = t[sq * 4 + 2][d];
        o.w = t[sq * 4 + 3][d];
        *(ushort4*)(Vt + (size_t)(bh * 64 + d) * SEQ + s0 + sq * 4) = o;
    }
}

// --- MFMA flash attention: 64 q/block (16 q/wave), S^T, 2-buf vmcnt(4) pipeline ---
// 1024 blocks, 40KB LDS -> 4 blocks/CU (16 waves/CU) for latency hiding.
__global__ __launch_bounds__(256) void attn_kernel(const unsigned short* __restrict__ QKV,
                                                   const unsigned short* __restrict__ Vt,
                                                   unsigned short* __restrict__ O) {
    __shared__ unsigned short smem[2 * 8192 + 4 * 16 * 64];

    int tid = threadIdx.x;
    int wave = tid >> 6, lane = tid & 63;
    int quad = lane >> 4, m16 = lane & 15;
    int m7 = m16 & 7;
    int b = blockIdx.y >> 4, h = blockIdx.y & 15;
    int q0 = blockIdx.x * 64;

    const unsigned short* Qg = QKV + (size_t)b * SEQ * QKVS + h * 64;
    const unsigned short* Kg = QKV + (size_t)b * SEQ * QKVS + 1024 + h * 64;
    const unsigned short* Vtg = Vt + (size_t)blockIdx.y * 64 * SEQ;
    unsigned short* Pw = smem + 2 * 8192 + wave * 16 * 64;

    const float QSC = 0.125f * 1.44269504f;
    bf16x8 aq[2];
    {
        int qrow = q0 + wave * 16 + m16;
#pragma unroll
        for (int s = 0; s < 2; s++) {
            bf16x8 t = *(const bf16x8*)(Qg + (size_t)qrow * QKVS + s * 32 + quad * 8);
#pragma unroll
            for (int j = 0; j < 8; j++) t[j] = (__bf16)((float)t[j] * QSC);
            aq[s] = t;
        }
    }

    f32x4 on[4];
#pragma unroll
    for (int nb = 0; nb < 4; nb++) on[nb] = (f32x4){0.f, 0.f, 0.f, 0.f};
    float lsum = 0.f;

    auto stage = [&](int t, int buf) {
        unsigned short* Kb = smem + buf * 8192;
        unsigned short* Vb = Kb + 4096;
        int j0 = t * 64;
#pragma unroll
        for (int rnd = 0; rnd < 2; rnd++) {
            int C = rnd * 256 + wave * 64 + lane;
            int row = C >> 3;
            int cc = (C & 7) ^ (row & 7);
            gl_lds16(Kg + (size_t)(j0 + row) * QKVS + cc * 8, Kb + (rnd * 256 + wave * 64) * 8);
            gl_lds16(Vtg + (size_t)row * SEQ + j0 + cc * 8, Vb + (rnd * 256 + wave * 64) * 8);
        }
    };

    stage(0, 0);
    int buf = 0;
    for (int t = 0; t < SEQ / 64; t++) {
        if (t < SEQ / 64 - 1) {
            stage(t + 1, buf ^ 1);
            __asm__ volatile("s_waitcnt vmcnt(4)" ::: "memory");
        } else {
            __asm__ volatile("s_waitcnt vmcnt(0)" ::: "memory");
        }
        __builtin_amdgcn_s_barrier();
        unsigned short* Kb = smem + buf * 8192;
        unsigned short* Vb = Kb + 4096;

        // S^T = K Q^T : D[key][q] (lane=q, regs=keys)
        f32x4 sacc[4];
#pragma unroll
        for (int nb = 0; nb < 4; nb++) sacc[nb] = (f32x4){0.f, 0.f, 0.f, 0.f};
#pragma unroll
        for (int s = 0; s < 2; s++) {
#pragma unroll
            for (int nb = 0; nb < 4; nb++) {
                int r = nb * 16 + m16;
                bf16x8 bk = *(const bf16x8*)&Kb[r * 64 + (((s * 4 + quad) ^ (r & 7)) * 8)];
                sacc[nb] = __builtin_amdgcn_mfma_f32_16x16x32_bf16(bk, aq[s], sacc[nb], 0, 0, 0);
            }
        }

        // P = exp2(S^T); per-lane partial sums; packed cvt; swizzled b64 writes
        float part = 0.f;
#pragma unroll
        for (int nb = 0; nb < 4; nb++) {
            f32x4 pv;
            pv[0] = EXP2(sacc[nb][0]);
            pv[1] = EXP2(sacc[nb][1]);
            pv[2] = EXP2(sacc[nb][2]);
            pv[3] = EXP2(sacc[nb][3]);
            part += (pv[0] + pv[1]) + (pv[2] + pv[3]);
            bf16x4v pb = __builtin_convertvector(pv, bf16x4v);
            *(bf16x4v*)&Pw[m16 * 64 + (((nb * 2 + (quad >> 1)) ^ m7) * 8) + (quad & 1) * 4] = pb;
        }
        lsum += part;
        __asm__ volatile("s_waitcnt lgkmcnt(0)" ::: "memory");

        // O += P V
#pragma unroll
        for (int s = 0; s < 2; s++) {
            bf16x8 ap = *(const bf16x8*)&Pw[m16 * 64 + (((s * 4 + quad) ^ m7) * 8)];
#pragma unroll
            for (int nb = 0; nb < 4; nb++) {
                int r = nb * 16 + m16;
                bf16x8 bv = *(const bf16x8*)&Vb[r * 64 + (((s * 4 + quad) ^ (r & 7)) * 8)];
                on[nb] = __builtin_amdgcn_mfma_f32_16x16x32_bf16(ap, bv, on[nb], 0, 0, 0);
            }
        }
        __builtin_amdgcn_s_barrier();
        buf ^= 1;
    }

    // epilogue: per-q sums live at lanes m16==q after reducing lane bits 4,5
    {
        float s2 = lsum;
        s2 += __shfl_xor(s2, 16, 64);
        s2 += __shfl_xor(s2, 32, 64);
#pragma unroll
        for (int r = 0; r < 4; r++) {
            float inv = 1.0f / __shfl(s2, quad * 4 + r, 64);
            size_t rowo =
                (size_t)(b * SEQ + q0 + wave * 16 + quad * 4 + r) * DMODEL + h * 64;
#pragma unroll
            for (int nb = 0; nb < 4; nb++)
                O[rowo + nb * 16 + m16] = f2bf(on[nb][r] * inv);
        }
    }
}

extern "C" void kernel_launch(void* const* d_in, const int* in_sizes, int n_in,
                              void* d_out, int out_size, void* d_ws, size_t ws_size,
                              hipStream_t stream) {
    const float* X = (const float*)d_in[0];
    const float* Wq = (const float*)d_in[1];
    const float* Wk = (const float*)d_in[2];
    const float* Wv = (const float*)d_in[3];
    const float* Wo = (const float*)d_in[4];
    const float* W1 = (const float*)d_in[5];
    const float* b1 = (const float*)d_in[6];
    const float* W2 = (const float*)d_in[7];
    const float* b2 = (const float*)d_in[8];
    const float* g1 = (const float*)d_in[9];
    const float* be1 = (const float*)d_in[10];
    const float* g2 = (const float*)d_in[11];
    const float* be2 = (const float*)d_in[12];
    float* out = (float*)d_out;

    char* ws = (char*)d_ws;
    auto MB = [](size_t x) { return x << 20; };
    unsigned short* WqkvT = (unsigned short*)(ws + MB(0));
    unsigned short* WqT = WqkvT;
    unsigned short* WkT = (unsigned short*)(ws + MB(2));
    unsigned short* WvT = (unsigned short*)(ws + MB(4));
    unsigned short* WoT = (unsigned short*)(ws + MB(6));
    unsigned short* W1T = (unsigned short*)(ws + MB(8));
    unsigned short* W2T = (unsigned short*)(ws + MB(16));
    unsigned short* nX = (unsigned short*)(ws + MB(24));
    unsigned short* QKVb = (unsigned short*)(ws + MB(32));
    unsigned short* Cx = (unsigned short*)(ws + MB(56));
    unsigned short* Vtb = (unsigned short*)(ws + MB(64));
    unsigned short* Hb = (unsigned short*)(ws + MB(32));
    unsigned short* P0 = (unsigned short*)(ws + MB(24));  // nX dead at FFN2
    unsigned short* P1 = (unsigned short*)(ws + MB(64));  // Vt dead at FFN2

    dim3 blk(256);

    // weight transposes + LN1, one launch
    pre_kernel<<<dim3(16384), blk, 0, stream>>>(Wq, Wk, Wv, Wo, W1, W2,
                                                WqT, WkT, WvT, WoT, W1T, W2T,
                                                X, g1, be1, nX);

    dim3 gQKV(QKVS / 128, ROWS / 128);      // 768 blocks
    dim3 gD64(DMODEL / 64, ROWS / 128);     // 512 blocks
    dim3 gF(FFDIM / 128, ROWS / 128);       // 1024 blocks
    dim3 gSK(DMODEL / 128, ROWS / 128, 2);  // 512 blocks

    // fused QKV projection
    mm_kernel<EP_BF16><<<gQKV, blk, 0, stream>>>(nX, WqkvT, nullptr, nullptr, QKVb, nullptr,
                                                 ROWS, QKVS, DMODEL);
    // V transpose for PV B-operand
    vtrans_kernel<<<dim3(SEQ / 64, 2 * NHEAD), blk, 0, stream>>>(QKVb, Vtb);
    // flash attention (64 q/block, pipelined, 4 blocks/CU)
    attn_kernel<<<dim3(SEQ / 64, 2 * NHEAD), blk, 0, stream>>>(QKVb, Vtb, Cx);
    // out = ctx @ Wo + X
    mm64_kernel<EP_RESID_F32><<<gD64, blk, 0, stream>>>(Cx, WoT, nullptr, X, nullptr, out,
                                                        ROWS, DMODEL, DMODEL);
    ln_kernel<<<ROWS, blk, 0, stream>>>(out, g2, be2, nX);
    // h = relu(nX @ W1 + b1)
    mm_kernel<EP_RELUBIAS_BF16><<<gF, blk, 0, stream>>>(nX, W1T, b1, nullptr, Hb, nullptr,
                                                        ROWS, FFDIM, DMODEL);
    // FFN2 split-K=2: partials (bf16) then out += P0+P1+b2
    mmsk_kernel<<<gSK, blk, 0, stream>>>(Hb, W2T, P0, P1, ROWS, DMODEL, FFDIM);
    red2_kernel<<<dim3(4096), blk, 0, stream>>>(P0, P1, b2, out);
}